// Round 6
// baseline (800.455 us; speedup 1.0000x reference)
//
#include <hip/hip_runtime.h>
#include <hip/hip_bf16.h>
#include <math.h>

#define NHEADS 16
#define HD     128
#define CEMB   2048
#define BATCH  4
#define TSEQ   2048

typedef __attribute__((ext_vector_type(8))) short bf16x8;
typedef __attribute__((ext_vector_type(4))) float f32x4;

#define NEGF (-1.0e30f)
// fp64 fixup window in score units. 4-term bf16-split MFMA leaves only f32
// accumulation error (~5e-6 worst in score units).
#define WIN  4.0e-5f

__device__ inline short f2bf(float x) {
    __hip_bfloat16 h = __float2bfloat16(x);
    return *reinterpret_cast<short*>(&h);
}
__device__ inline void split2(float x, short& hi, short& lo) {
    __hip_bfloat16 h = __float2bfloat16(x);
    float hf = __bfloat162float(h);
    __hip_bfloat16 l = __float2bfloat16(x - hf);
    hi = *reinterpret_cast<short*>(&h);
    lo = *reinterpret_cast<short*>(&l);
}

// Per-CU balance map: CU gets blocks id, id+256, id+512, id+768 (round-robin);
// slots {s,s+4,s+8,s+12} must sum to equal work. QMAP gives each CU 34 units.
__device__ __constant__ int QMAP[16] = {15,14,13,12, 8,9,10,11, 7,6,5,4, 0,1,2,3};

// ---------------- MFMA flash attention with exact-floor scores ----------------
// 1D grid 1024, 512-thread blocks = 8 waves. Block = 128 q-rows; wave owns 16
// rows (ONE 16-row sub-tile). K-tiles of 32.
// r6: s-dimension split across waves (was 4 waves x 32 rows). Persistent state
// per wave: qhi/qlo 32 + oacc 32 = 64 regs -> total ~110 <= 128 unified ->
// launch_bounds(512,4) = 16 waves/CU (was 8 at 192 regs). Same LDS, same
// staging volume, 2x latency hiding.
// History: r0 (256,4) spilled; r2 reg-prefetch spilled; r3 DMA+convert lost;
// r4/r5: __expf + 4-term split + defer-rescale -> 452us.
__global__ __launch_bounds__(512, 4)
void attn_mfma(const float* __restrict__ Q, const float* __restrict__ K,
               const float* __restrict__ V, __hip_bfloat16* __restrict__ O)
{
    __shared__ __align__(16) short Khi[32][136];
    __shared__ __align__(16) short Klo[32][136];
    // Vt[hd][k]: 64B rows, group-swizzled: k-group g of row hd stored at
    // position g ^ ((hd>>2)&3). k-order inside groups preserved -> MFMA-legal.
    __shared__ __align__(16) short Vt[128][32];
    __shared__ __align__(16) short Ps[8][16][40];

    const int tid  = threadIdx.x;
    const int wave = tid >> 6;     // 0..7
    const int lane = tid & 63;
    const int quad = lane >> 4;
    const int n    = lane & 15;

    const int id   = blockIdx.x;
    const int bh   = id & 63;
    const int qblk = QMAP[id >> 6];
    const int b    = bh >> 4;
    const int h    = bh & 15;
    const int q0w  = qblk * 128 + wave * 16;   // wave's 16-row sub-tile

    const size_t inbase = ((size_t)b * TSEQ) * CEMB + (size_t)h * HD;

    const float  scale     = sqrtf(128.0f);
    const double dscale    = (double)scale;
    const float  inv_scale = 1.0f / scale;

    // ---- Q fragments (resident): hi/lo bf16 split; A-frag row = n ----
    bf16x8 qhi[4], qlo[4];
    #pragma unroll
    for (int ks = 0; ks < 4; ++ks) {
        const float* qp = Q + inbase + (size_t)(q0w + n) * CEMB + 32 * ks + 8 * quad;
        float4 f0 = *(const float4*)qp;
        float4 f1 = *(const float4*)(qp + 4);
        float fv[8] = {f0.x, f0.y, f0.z, f0.w, f1.x, f1.y, f1.z, f1.w};
        bf16x8 h8, l8;
        #pragma unroll
        for (int j = 0; j < 8; ++j) {
            short hj, lj;
            split2(fv[j], hj, lj);
            h8[j] = hj; l8[j] = lj;
        }
        qhi[ks] = h8;
        qlo[ks] = l8;
    }

    f32x4 oacc[8];
    #pragma unroll
    for (int nt = 0; nt < 8; ++nt)
        oacc[nt] = (f32x4){0.f, 0.f, 0.f, 0.f};

    float m_r[4], l_r[4];
    #pragma unroll
    for (int reg = 0; reg < 4; ++reg) { m_r[reg] = NEGF; l_r[reg] = 0.f; }

    const int nkt = 4 * (qblk + 1);

    for (int kt = 0; kt < nkt; ++kt) {
        const int k0 = kt * 32;
        __syncthreads();
        // ---- stage K (hi/lo split) and V (bf16, transposed + swizzled) ----
        #pragma unroll
        for (int it = 0; it < 2; ++it) {
            int idx = tid + 512 * it;      // 0..1023
            int r   = idx >> 5;            // 0..31
            int c4  = idx & 31;            // float4 within row
            size_t off = inbase + (size_t)(k0 + r) * CEMB + 4 * c4;
            float4 kv = *(const float4*)(K + off);
            float4 vv = *(const float4*)(V + off);
            short4 khi4, klo4;
            split2(kv.x, khi4.x, klo4.x); split2(kv.y, khi4.y, klo4.y);
            split2(kv.z, khi4.z, klo4.z); split2(kv.w, khi4.w, klo4.w);
            *(short4*)&Khi[r][4 * c4] = khi4;
            *(short4*)&Klo[r][4 * c4] = klo4;
            int pos = 8 * ((r >> 3) ^ (c4 & 3)) + (r & 7);
            Vt[4 * c4 + 0][pos] = f2bf(vv.x);
            Vt[4 * c4 + 1][pos] = f2bf(vv.y);
            Vt[4 * c4 + 2][pos] = f2bf(vv.z);
            Vt[4 * c4 + 3][pos] = f2bf(vv.w);
        }
        __syncthreads();

        if (k0 <= q0w + 15) {   // causal: wave has live rows in this K-tile
            // ---- S = Q·K^T via 4-term bf16-split MFMA (exact to accum error) ----
            f32x4 sacc[2];
            sacc[0] = (f32x4){0.f, 0.f, 0.f, 0.f};
            sacc[1] = (f32x4){0.f, 0.f, 0.f, 0.f};

            __builtin_amdgcn_s_setprio(1);
            #pragma unroll
            for (int ks = 0; ks < 4; ++ks) {
                #pragma unroll
                for (int nt = 0; nt < 2; ++nt) {
                    bf16x8 khf = *(const bf16x8*)&Khi[16 * nt + n][32 * ks + 8 * quad];
                    bf16x8 klf = *(const bf16x8*)&Klo[16 * nt + n][32 * ks + 8 * quad];
                    sacc[nt] = __builtin_amdgcn_mfma_f32_16x16x32_bf16(qhi[ks], khf, sacc[nt], 0, 0, 0);
                    sacc[nt] = __builtin_amdgcn_mfma_f32_16x16x32_bf16(qhi[ks], klf, sacc[nt], 0, 0, 0);
                    sacc[nt] = __builtin_amdgcn_mfma_f32_16x16x32_bf16(qlo[ks], khf, sacc[nt], 0, 0, 0);
                    sacc[nt] = __builtin_amdgcn_mfma_f32_16x16x32_bf16(qlo[ks], klf, sacc[nt], 0, 0, 0);
                }
            }
            __builtin_amdgcn_s_setprio(0);

            // ---- floor + fp64 boundary fixup + online softmax, write P ----
            float sc[2][4];
            #pragma unroll
            for (int nt = 0; nt < 2; ++nt) {
                #pragma unroll
                for (int reg = 0; reg < 4; ++reg) {
                    int qrow = q0w + 4 * quad + reg;
                    int kcol = k0 + 16 * nt + n;
                    if (kcol > qrow) { sc[nt][reg] = NEGF; continue; }
                    float sv = sacc[nt][reg] * inv_scale;
                    float f  = floorf(sv);
                    float fr = sv - f;
                    if (fr < WIN || fr > 1.0f - WIN) {
                        // vectorized fp64 re-check: 4 independent chains
                        const float4* qp4 = (const float4*)(Q + inbase + (size_t)qrow * CEMB);
                        const float4* kp4 = (const float4*)(K + inbase + (size_t)kcol * CEMB);
                        double d0 = 0.0, d1 = 0.0, d2 = 0.0, d3 = 0.0;
                        #pragma unroll 2
                        for (int kk = 0; kk < HD / 4; ++kk) {
                            float4 aq = qp4[kk];
                            float4 bk = kp4[kk];
                            d0 += (double)aq.x * bk.x;
                            d1 += (double)aq.y * bk.y;
                            d2 += (double)aq.z * bk.z;
                            d3 += (double)aq.w * bk.w;
                        }
                        f = (float)floor(((d0 + d1) + (d2 + d3)) / dscale);
                    }
                    sc[nt][reg] = f;
                }
            }
            // scores are floored integers; exp args are ints <= 0.
            // __expf = v_mul + v_exp_f32; exp(-1e30) underflows to 0 -> no
            // NEGF guards needed. (mn always finite: entered tiles have a
            // live column for every row from tile 0 on.)
            float alphaL[4];
            #pragma unroll
            for (int reg = 0; reg < 4; ++reg) {
                float tm = fmaxf(sc[0][reg], sc[1][reg]);
                tm = fmaxf(tm, __shfl_xor(tm, 1));
                tm = fmaxf(tm, __shfl_xor(tm, 2));
                tm = fmaxf(tm, __shfl_xor(tm, 4));
                tm = fmaxf(tm, __shfl_xor(tm, 8));
                float mo = m_r[reg];
                float mn = fmaxf(mo, tm);
                float al = __expf(mo - mn);
                float p0 = __expf(sc[0][reg] - mn);
                float p1 = __expf(sc[1][reg] - mn);
                float ps = p0 + p1;
                ps += __shfl_xor(ps, 1);
                ps += __shfl_xor(ps, 2);
                ps += __shfl_xor(ps, 4);
                ps += __shfl_xor(ps, 8);
                l_r[reg] = l_r[reg] * al + ps;
                m_r[reg] = mn;
                alphaL[reg] = al;
                Ps[wave][4 * quad + reg][n]      = f2bf(p0);
                Ps[wave][4 * quad + reg][16 + n] = f2bf(p1);
            }
            // T13 defer-rescale: alphas are exp(integer diff) == 1.0f exactly
            // when the running max didn't grow (common case).
            if (!__all(alphaL[0] == 1.0f && alphaL[1] == 1.0f &&
                       alphaL[2] == 1.0f && alphaL[3] == 1.0f)) {
                #pragma unroll
                for (int ntv = 0; ntv < 8; ++ntv) {
                    #pragma unroll
                    for (int reg = 0; reg < 4; ++reg)
                        oacc[ntv][reg] *= alphaL[reg];
                }
            }

            // ---- O += P·V: A-frag from Ps, B-frag b128 from swizzled Vt ----
            bf16x8 pfa = *(const bf16x8*)&Ps[wave][n][8 * quad];
            __builtin_amdgcn_s_setprio(1);
            #pragma unroll
            for (int ntv = 0; ntv < 8; ++ntv) {
                bf16x8 vf = *(const bf16x8*)&Vt[16 * ntv + n][8 * (quad ^ (n >> 2))];
                oacc[ntv] = __builtin_amdgcn_mfma_f32_16x16x32_bf16(pfa, vf, oacc[ntv], 0, 0, 0);
            }
            __builtin_amdgcn_s_setprio(0);
        }
    }

    // ---- normalize + write bf16 merged-head layout [b, t, h*128 + c] ----
    #pragma unroll
    for (int reg = 0; reg < 4; ++reg) {
        float inv = 1.0f / l_r[reg];
        int qrow = q0w + 4 * quad + reg;
        __hip_bfloat16* op = O + ((size_t)b * TSEQ + qrow) * CEMB + (size_t)h * HD;
        #pragma unroll
        for (int ntv = 0; ntv < 8; ++ntv)
            op[16 * ntv + n] = __float2bfloat16(oacc[ntv][reg] * inv);
    }
}

// ---------------- W fp32 -> bf16 one-shot conversion ----------------
__global__ __launch_bounds__(256)
void wconv(const float* __restrict__ W, __hip_bfloat16* __restrict__ Wb)
{
    size_t i = ((size_t)blockIdx.x * 256 + threadIdx.x) * 4;
    float4 w = *(const float4*)(W + i);
    short4 s4;
    s4.x = f2bf(w.x); s4.y = f2bf(w.y); s4.z = f2bf(w.z); s4.w = f2bf(w.w);
    *(short4*)(Wb + i) = s4;
}

// ---------------- projection: out = X(bf16) @ Wb(bf16)^T + bias ----------------
// Tile 128x128, K-slab 32. Block 256 = 4 waves in 2x2; wave does 64x64 via
// 4x4 sub-tiles of 16x16x32. r6: W pre-converted to bf16 -> staging is pure
// bf16x8 copies (no per-slab fp32->bf16 VALU).
__global__ __launch_bounds__(256)
void proj_bf16w(const __hip_bfloat16* __restrict__ X, const __hip_bfloat16* __restrict__ Wb,
                const float* __restrict__ bias, float* __restrict__ out)
{
    __shared__ __align__(16) short Xs[128][40];
    __shared__ __align__(16) short Ws[128][40];

    const int tid  = threadIdx.x;
    const int wave = tid >> 6;
    const int lane = tid & 63;
    const int quad = lane >> 4;
    const int n    = lane & 15;
    const int wm   = wave >> 1;
    const int wn   = wave & 1;

    const int m0 = blockIdx.y * 128;
    const int n0 = blockIdx.x * 128;

    f32x4 acc[4][4];
    #pragma unroll
    for (int i = 0; i < 4; ++i)
        #pragma unroll
        for (int j = 0; j < 4; ++j)
            acc[i][j] = (f32x4){0.f, 0.f, 0.f, 0.f};

    for (int k0 = 0; k0 < CEMB; k0 += 32) {
        __syncthreads();
        // X and W: bf16 direct, 512 16B-chunks each
        #pragma unroll
        for (int ii = 0; ii < 2; ++ii) {
            int idx = tid + 256 * ii;          // 0..511
            int row = idx >> 2;                // 0..127
            int c   = idx & 3;                 // 16B group
            *(bf16x8*)&Xs[row][8 * c] =
                *(const bf16x8*)(X + (size_t)(m0 + row) * CEMB + k0 + 8 * c);
            *(bf16x8*)&Ws[row][8 * c] =
                *(const bf16x8*)(Wb + (size_t)(n0 + row) * CEMB + k0 + 8 * c);
        }
        __syncthreads();

        bf16x8 a[4], bb[4];
        #pragma unroll
        for (int i = 0; i < 4; ++i)
            a[i] = *(const bf16x8*)&Xs[64 * wm + 16 * i + n][8 * quad];
        #pragma unroll
        for (int j = 0; j < 4; ++j)
            bb[j] = *(const bf16x8*)&Ws[64 * wn + 16 * j + n][8 * quad];
        __builtin_amdgcn_s_setprio(1);
        #pragma unroll
        for (int i = 0; i < 4; ++i)
            #pragma unroll
            for (int j = 0; j < 4; ++j)
                acc[i][j] = __builtin_amdgcn_mfma_f32_16x16x32_bf16(a[i], bb[j], acc[i][j], 0, 0, 0);
        __builtin_amdgcn_s_setprio(0);
    }

    #pragma unroll
    for (int j = 0; j < 4; ++j) {
        int col = n0 + 64 * wn + 16 * j + n;
        float bj = bias[col];
        #pragma unroll
        for (int i = 0; i < 4; ++i) {
            #pragma unroll
            for (int reg = 0; reg < 4; ++reg) {
                int row = m0 + 64 * wm + 16 * i + 4 * quad + reg;
                out[(size_t)row * CEMB + col] = acc[i][j][reg] + bj;
            }
        }
    }
}

// ---------------- fallback projection with fp32 W (small ws_size) ----------------
__global__ __launch_bounds__(256)
void proj_mfma(const __hip_bfloat16* __restrict__ X, const float* __restrict__ W,
               const float* __restrict__ bias, float* __restrict__ out)
{
    __shared__ __align__(16) short Xs[128][40];
    __shared__ __align__(16) short Ws[128][40];

    const int tid  = threadIdx.x;
    const int wave = tid >> 6;
    const int lane = tid & 63;
    const int quad = lane >> 4;
    const int n    = lane & 15;
    const int wm   = wave >> 1;
    const int wn   = wave & 1;

    const int m0 = blockIdx.y * 128;
    const int n0 = blockIdx.x * 128;

    f32x4 acc[4][4];
    #pragma unroll
    for (int i = 0; i < 4; ++i)
        #pragma unroll
        for (int j = 0; j < 4; ++j)
            acc[i][j] = (f32x4){0.f, 0.f, 0.f, 0.f};

    for (int k0 = 0; k0 < CEMB; k0 += 32) {
        __syncthreads();
        #pragma unroll
        for (int ii = 0; ii < 2; ++ii) {
            int idx = tid + 256 * ii;
            int row = idx >> 2;
            int c   = idx & 3;
            *(bf16x8*)&Xs[row][8 * c] =
                *(const bf16x8*)(X + (size_t)(m0 + row) * CEMB + k0 + 8 * c);
        }
        #pragma unroll
        for (int ii = 0; ii < 4; ++ii) {
            int idx = tid + 256 * ii;
            int row = idx >> 3;
            int c4  = idx & 7;
            float4 wv = *(const float4*)(W + (size_t)(n0 + row) * CEMB + k0 + 4 * c4);
            short4 w4;
            w4.x = f2bf(wv.x); w4.y = f2bf(wv.y); w4.z = f2bf(wv.z); w4.w = f2bf(wv.w);
            *(short4*)&Ws[row][4 * c4] = w4;
        }
        __syncthreads();

        bf16x8 a[4], bb[4];
        #pragma unroll
        for (int i = 0; i < 4; ++i)
            a[i] = *(const bf16x8*)&Xs[64 * wm + 16 * i + n][8 * quad];
        #pragma unroll
        for (int j = 0; j < 4; ++j)
            bb[j] = *(const bf16x8*)&Ws[64 * wn + 16 * j + n][8 * quad];
        #pragma unroll
        for (int i = 0; i < 4; ++i)
            #pragma unroll
            for (int j = 0; j < 4; ++j)
                acc[i][j] = __builtin_amdgcn_mfma_f32_16x16x32_bf16(a[i], bb[j], acc[i][j], 0, 0, 0);
    }

    #pragma unroll
    for (int j = 0; j < 4; ++j) {
        int col = n0 + 64 * wn + 16 * j + n;
        float bj = bias[col];
        #pragma unroll
        for (int i = 0; i < 4; ++i) {
            #pragma unroll
            for (int reg = 0; reg < 4; ++reg) {
                int row = m0 + 64 * wm + 16 * i + 4 * quad + reg;
                out[(size_t)row * CEMB + col] = acc[i][j][reg] + bj;
            }
        }
    }
}

extern "C" void kernel_launch(void* const* d_in, const int* in_sizes, int n_in,
                              void* d_out, int out_size, void* d_ws, size_t ws_size,
                              hipStream_t stream)
{
    // setup_inputs order: v, k, q, W_out, b_out
    const float* v    = (const float*)d_in[0];
    const float* k    = (const float*)d_in[1];
    const float* q    = (const float*)d_in[2];
    const float* W    = (const float*)d_in[3];
    const float* bias = (const float*)d_in[4];

    const size_t attn_bytes = (size_t)BATCH * TSEQ * CEMB * 2;   // 32 MiB
    const size_t wb_bytes   = (size_t)CEMB * CEMB * 2;           //  8 MiB

    __hip_bfloat16* attn = (__hip_bfloat16*)d_ws;
    float* out = (float*)d_out;

    dim3 pgrid(CEMB / 128, (BATCH * TSEQ) / 128);   // (16, 64)

    if (ws_size >= attn_bytes + wb_bytes) {
        __hip_bfloat16* Wb = (__hip_bfloat16*)((char*)d_ws + attn_bytes);
        wconv<<<dim3(CEMB * CEMB / 1024), 256, 0, stream>>>(W, Wb);
        attn_mfma<<<dim3(1024), 512, 0, stream>>>(q, k, v, attn);
        proj_bf16w<<<pgrid, 256, 0, stream>>>(attn, Wb, bias, out);
    } else {
        attn_mfma<<<dim3(1024), 512, 0, stream>>>(q, k, v, attn);
        proj_mfma<<<pgrid, 256, 0, stream>>>(attn, W, bias, out);
    }
}

// Round 7
// 695.028 us; speedup vs baseline: 1.1517x; 1.1517x over previous
//
#include <hip/hip_runtime.h>
#include <hip/hip_bf16.h>
#include <math.h>

#define NHEADS 16
#define HD     128
#define CEMB   2048
#define BATCH  4
#define TSEQ   2048

typedef __attribute__((ext_vector_type(8))) short bf16x8;
typedef __attribute__((ext_vector_type(4))) float f32x4;

#define NEGF (-1.0e30f)
// fp64 fixup window in score units. 4-term bf16-split MFMA leaves only f32
// accumulation error (~5e-6 worst in score units).
#define WIN  4.0e-5f

__device__ inline short f2bf(float x) {
    __hip_bfloat16 h = __float2bfloat16(x);
    return *reinterpret_cast<short*>(&h);
}
__device__ inline void split2(float x, short& hi, short& lo) {
    __hip_bfloat16 h = __float2bfloat16(x);
    float hf = __bfloat162float(h);
    __hip_bfloat16 l = __float2bfloat16(x - hf);
    hi = *reinterpret_cast<short*>(&h);
    lo = *reinterpret_cast<short*>(&l);
}

// Per-CU balance map: CU gets blocks id, id+256, id+512, id+768 (round-robin);
// slots {s,s+4,s+8,s+12} must sum to equal work. QMAP gives each CU 34 units.
__device__ __constant__ int QMAP[16] = {15,14,13,12, 8,9,10,11, 7,6,5,4, 0,1,2,3};

// ---------------- one-shot K/V pre-split + pre-transpose ----------------
// Each K/V 32-row tile was being re-converted (split2/f2bf) by 16 qblk-blocks.
// Do it ONCE: Khig/Klog = bf16 hi/lo row-major [bh][t][128];
// Vtg = the exact transposed+swizzled LDS image per tile [bh][kt][128][32].
__global__ __launch_bounds__(256)
void kvconv(const float* __restrict__ K, const float* __restrict__ V,
            __hip_bfloat16* __restrict__ Khig, __hip_bfloat16* __restrict__ Klog,
            __hip_bfloat16* __restrict__ Vtg)
{
    __shared__ __align__(16) short KhiL[32][136];
    __shared__ __align__(16) short KloL[32][136];
    __shared__ __align__(16) short VtL[128][32];

    const int tid = threadIdx.x;
    const int bh  = blockIdx.x & 63;
    const int kt  = blockIdx.x >> 6;      // 0..63
    const int b   = bh >> 4;
    const int h   = bh & 15;
    const int k0  = kt * 32;
    const size_t inbase = ((size_t)b * TSEQ) * CEMB + (size_t)h * HD;

    #pragma unroll
    for (int it = 0; it < 4; ++it) {
        int idx = tid + 256 * it;       // 0..1023
        int r   = idx >> 5;             // 0..31
        int c4  = idx & 31;
        size_t off = inbase + (size_t)(k0 + r) * CEMB + 4 * c4;
        float4 kv = *(const float4*)(K + off);
        float4 vv = *(const float4*)(V + off);
        short4 khi4, klo4;
        split2(kv.x, khi4.x, klo4.x); split2(kv.y, khi4.y, klo4.y);
        split2(kv.z, khi4.z, klo4.z); split2(kv.w, khi4.w, klo4.w);
        *(short4*)&KhiL[r][4 * c4] = khi4;
        *(short4*)&KloL[r][4 * c4] = klo4;
        int pos = 8 * ((r >> 3) ^ (c4 & 3)) + (r & 7);
        VtL[4 * c4 + 0][pos] = f2bf(vv.x);
        VtL[4 * c4 + 1][pos] = f2bf(vv.y);
        VtL[4 * c4 + 2][pos] = f2bf(vv.z);
        VtL[4 * c4 + 3][pos] = f2bf(vv.w);
    }
    __syncthreads();

    short* khg = (short*)Khig + ((size_t)bh * TSEQ + k0) * 128;
    short* klg = (short*)Klog + ((size_t)bh * TSEQ + k0) * 128;
    short* vtg = (short*)Vtg + ((size_t)(bh * 64 + kt)) * 4096;
    #pragma unroll
    for (int i = 0; i < 2; ++i) {
        int idx = tid + 256 * i;        // 0..511 chunks of 8 shorts
        int r   = idx >> 4;             // 0..31
        int c8  = idx & 15;
        *(bf16x8*)(khg + r * 128 + 8 * c8) = *(const bf16x8*)&KhiL[r][8 * c8];
        *(bf16x8*)(klg + r * 128 + 8 * c8) = *(const bf16x8*)&KloL[r][8 * c8];
        *(bf16x8*)(vtg + idx * 8)          = *(const bf16x8*)&((short*)VtL)[idx * 8];
    }
}

// ---------------- MFMA flash attention with exact-floor scores ----------------
// r7: r5 structure (4 waves x 32 rows, (256,2)) + pre-split bf16 K/V staging:
// 6 bf16x8 loads + 6 b128 LDS writes per thread per tile, ZERO conversion VALU.
// History: r0 (256,4) spill; r2 reg-prefetch spill; r3 DMA+convert lost;
// r5: __expf + 4-term + defer-rescale -> 452us; r6 8-wave split spilled/lost.
__global__ __launch_bounds__(256, 2)
void attn_mfma(const float* __restrict__ Q, const float* __restrict__ K,
               const __hip_bfloat16* __restrict__ Khig,
               const __hip_bfloat16* __restrict__ Klog,
               const __hip_bfloat16* __restrict__ Vtg,
               __hip_bfloat16* __restrict__ O)
{
    __shared__ __align__(16) short Khi[32][136];
    __shared__ __align__(16) short Klo[32][136];
    __shared__ __align__(16) short Vt[128][32];
    __shared__ __align__(16) short Ps[4][32][40];

    const int tid  = threadIdx.x;
    const int wave = tid >> 6;
    const int lane = tid & 63;
    const int quad = lane >> 4;
    const int n    = lane & 15;

    const int id   = blockIdx.x;
    const int bh   = id & 63;
    const int qblk = QMAP[id >> 6];
    const int b    = bh >> 4;
    const int h    = bh & 15;
    const int q0w  = qblk * 128 + wave * 32;

    const size_t inbase = ((size_t)b * TSEQ) * CEMB + (size_t)h * HD;

    const float  scale     = sqrtf(128.0f);
    const double dscale    = (double)scale;
    const float  inv_scale = 1.0f / scale;

    // ---- Q fragments (resident): hi/lo bf16 split ----
    bf16x8 qhi[2][4], qlo[2][4];
    #pragma unroll
    for (int s = 0; s < 2; ++s) {
        #pragma unroll
        for (int ks = 0; ks < 4; ++ks) {
            const float* qp = Q + inbase + (size_t)(q0w + 16 * s + n) * CEMB + 32 * ks + 8 * quad;
            float4 f0 = *(const float4*)qp;
            float4 f1 = *(const float4*)(qp + 4);
            float fv[8] = {f0.x, f0.y, f0.z, f0.w, f1.x, f1.y, f1.z, f1.w};
            bf16x8 h8, l8;
            #pragma unroll
            for (int j = 0; j < 8; ++j) {
                short hj, lj;
                split2(fv[j], hj, lj);
                h8[j] = hj; l8[j] = lj;
            }
            qhi[s][ks] = h8;
            qlo[s][ks] = l8;
        }
    }

    f32x4 oacc[2][8];
    #pragma unroll
    for (int s = 0; s < 2; ++s)
        #pragma unroll
        for (int nt = 0; nt < 8; ++nt)
            oacc[s][nt] = (f32x4){0.f, 0.f, 0.f, 0.f};

    float m_r[2][4], l_r[2][4];
    #pragma unroll
    for (int s = 0; s < 2; ++s)
        #pragma unroll
        for (int reg = 0; reg < 4; ++reg) { m_r[s][reg] = NEGF; l_r[s][reg] = 0.f; }

    const int nkt = 4 * (qblk + 1);

    for (int kt = 0; kt < nkt; ++kt) {
        const int k0 = kt * 32;
        __syncthreads();
        // ---- stage K hi/lo + Vt image: pure bf16 copies, no conversion ----
        {
            const short* khg = (const short*)Khig + ((size_t)bh * TSEQ + k0) * 128;
            const short* klg = (const short*)Klog + ((size_t)bh * TSEQ + k0) * 128;
            const short* vtg = (const short*)Vtg + ((size_t)(bh * 64 + kt)) * 4096;
            #pragma unroll
            for (int i = 0; i < 2; ++i) {
                int idx = tid + 256 * i;    // 0..511
                int r   = idx >> 4;
                int c8  = idx & 15;
                *(bf16x8*)&Khi[r][8 * c8]          = *(const bf16x8*)(khg + r * 128 + 8 * c8);
                *(bf16x8*)&Klo[r][8 * c8]          = *(const bf16x8*)(klg + r * 128 + 8 * c8);
                *(bf16x8*)&((short*)Vt)[idx * 8]   = *(const bf16x8*)(vtg + idx * 8);
            }
        }
        __syncthreads();

        if (k0 <= q0w + 31) {   // causal: wave has live rows in this K-tile
            // ---- S = Q·K^T via 4-term bf16-split MFMA (exact to accum error) ----
            f32x4 sacc[2][2];
            #pragma unroll
            for (int s = 0; s < 2; ++s)
                #pragma unroll
                for (int nt = 0; nt < 2; ++nt)
                    sacc[s][nt] = (f32x4){0.f, 0.f, 0.f, 0.f};

            __builtin_amdgcn_s_setprio(1);
            #pragma unroll
            for (int ks = 0; ks < 4; ++ks) {
                #pragma unroll
                for (int nt = 0; nt < 2; ++nt) {
                    bf16x8 khf = *(const bf16x8*)&Khi[16 * nt + n][32 * ks + 8 * quad];
                    bf16x8 klf = *(const bf16x8*)&Klo[16 * nt + n][32 * ks + 8 * quad];
                    #pragma unroll
                    for (int s = 0; s < 2; ++s) {
                        sacc[s][nt] = __builtin_amdgcn_mfma_f32_16x16x32_bf16(qhi[s][ks], khf, sacc[s][nt], 0, 0, 0);
                        sacc[s][nt] = __builtin_amdgcn_mfma_f32_16x16x32_bf16(qhi[s][ks], klf, sacc[s][nt], 0, 0, 0);
                        sacc[s][nt] = __builtin_amdgcn_mfma_f32_16x16x32_bf16(qlo[s][ks], khf, sacc[s][nt], 0, 0, 0);
                        sacc[s][nt] = __builtin_amdgcn_mfma_f32_16x16x32_bf16(qlo[s][ks], klf, sacc[s][nt], 0, 0, 0);
                    }
                }
            }
            __builtin_amdgcn_s_setprio(0);

            // ---- floor + fp64 boundary fixup + online softmax, write P ----
            #pragma unroll
            for (int s = 0; s < 2; ++s) {
                float sc[2][4];
                #pragma unroll
                for (int nt = 0; nt < 2; ++nt) {
                    #pragma unroll
                    for (int reg = 0; reg < 4; ++reg) {
                        int qrow = q0w + 16 * s + 4 * quad + reg;
                        int kcol = k0 + 16 * nt + n;
                        if (kcol > qrow) { sc[nt][reg] = NEGF; continue; }
                        float sv = sacc[s][nt][reg] * inv_scale;
                        float f  = floorf(sv);
                        float fr = sv - f;
                        if (fr < WIN || fr > 1.0f - WIN) {
                            // vectorized fp64 re-check: 4 independent chains
                            const float4* qp4 = (const float4*)(Q + inbase + (size_t)qrow * CEMB);
                            const float4* kp4 = (const float4*)(K + inbase + (size_t)kcol * CEMB);
                            double d0 = 0.0, d1 = 0.0, d2 = 0.0, d3 = 0.0;
                            #pragma unroll 2
                            for (int kk = 0; kk < HD / 4; ++kk) {
                                float4 aq = qp4[kk];
                                float4 bk = kp4[kk];
                                d0 += (double)aq.x * bk.x;
                                d1 += (double)aq.y * bk.y;
                                d2 += (double)aq.z * bk.z;
                                d3 += (double)aq.w * bk.w;
                            }
                            f = (float)floor(((d0 + d1) + (d2 + d3)) / dscale);
                        }
                        sc[nt][reg] = f;
                    }
                }
                // scores are floored integers; exp args are ints <= 0.
                // exp(-1e30) underflows to 0 -> no NEGF guards needed.
                float alphaL[4];
                #pragma unroll
                for (int reg = 0; reg < 4; ++reg) {
                    float tm = fmaxf(sc[0][reg], sc[1][reg]);
                    tm = fmaxf(tm, __shfl_xor(tm, 1));
                    tm = fmaxf(tm, __shfl_xor(tm, 2));
                    tm = fmaxf(tm, __shfl_xor(tm, 4));
                    tm = fmaxf(tm, __shfl_xor(tm, 8));
                    float mo = m_r[s][reg];
                    float mn = fmaxf(mo, tm);
                    float al = __expf(mo - mn);
                    float p0 = __expf(sc[0][reg] - mn);
                    float p1 = __expf(sc[1][reg] - mn);
                    float ps = p0 + p1;
                    ps += __shfl_xor(ps, 1);
                    ps += __shfl_xor(ps, 2);
                    ps += __shfl_xor(ps, 4);
                    ps += __shfl_xor(ps, 8);
                    l_r[s][reg] = l_r[s][reg] * al + ps;
                    m_r[s][reg] = mn;
                    alphaL[reg] = al;
                    Ps[wave][16 * s + 4 * quad + reg][n]      = f2bf(p0);
                    Ps[wave][16 * s + 4 * quad + reg][16 + n] = f2bf(p1);
                }
                // T13 defer-rescale: alphas are exp(integer diff) == 1.0f
                // exactly when the running max didn't grow (common case).
                if (!__all(alphaL[0] == 1.0f && alphaL[1] == 1.0f &&
                           alphaL[2] == 1.0f && alphaL[3] == 1.0f)) {
                    #pragma unroll
                    for (int ntv = 0; ntv < 8; ++ntv) {
                        #pragma unroll
                        for (int reg = 0; reg < 4; ++reg)
                            oacc[s][ntv][reg] *= alphaL[reg];
                    }
                }
            }

            // ---- O += P·V: A-frag from Ps, B-frag b128 from swizzled Vt ----
            bf16x8 pfa[2];
            pfa[0] = *(const bf16x8*)&Ps[wave][n][8 * quad];
            pfa[1] = *(const bf16x8*)&Ps[wave][16 + n][8 * quad];
            __builtin_amdgcn_s_setprio(1);
            #pragma unroll
            for (int ntv = 0; ntv < 8; ++ntv) {
                bf16x8 vf = *(const bf16x8*)&Vt[16 * ntv + n][8 * (quad ^ (n >> 2))];
                oacc[0][ntv] = __builtin_amdgcn_mfma_f32_16x16x32_bf16(pfa[0], vf, oacc[0][ntv], 0, 0, 0);
                oacc[1][ntv] = __builtin_amdgcn_mfma_f32_16x16x32_bf16(pfa[1], vf, oacc[1][ntv], 0, 0, 0);
            }
            __builtin_amdgcn_s_setprio(0);
        }
    }

    // ---- normalize + write bf16 merged-head layout [b, t, h*128 + c] ----
    #pragma unroll
    for (int s = 0; s < 2; ++s) {
        #pragma unroll
        for (int reg = 0; reg < 4; ++reg) {
            float inv = 1.0f / l_r[s][reg];
            int qrow = q0w + 16 * s + 4 * quad + reg;
            __hip_bfloat16* op = O + ((size_t)b * TSEQ + qrow) * CEMB + (size_t)h * HD;
            #pragma unroll
            for (int ntv = 0; ntv < 8; ++ntv)
                op[16 * ntv + n] = __float2bfloat16(oacc[s][ntv][reg] * inv);
        }
    }
}

// ---------------- fallback attention (r5): fp32 staging, small ws ----------------
__global__ __launch_bounds__(256, 2)
void attn_mfma_fb(const float* __restrict__ Q, const float* __restrict__ K,
                  const float* __restrict__ V, __hip_bfloat16* __restrict__ O)
{
    __shared__ __align__(16) short Khi[32][136];
    __shared__ __align__(16) short Klo[32][136];
    __shared__ __align__(16) short Vt[128][32];
    __shared__ __align__(16) short Ps[4][32][40];

    const int tid  = threadIdx.x;
    const int wave = tid >> 6;
    const int lane = tid & 63;
    const int quad = lane >> 4;
    const int n    = lane & 15;

    const int id   = blockIdx.x;
    const int bh   = id & 63;
    const int qblk = QMAP[id >> 6];
    const int b    = bh >> 4;
    const int h    = bh & 15;
    const int q0w  = qblk * 128 + wave * 32;

    const size_t inbase = ((size_t)b * TSEQ) * CEMB + (size_t)h * HD;

    const float  scale     = sqrtf(128.0f);
    const double dscale    = (double)scale;
    const float  inv_scale = 1.0f / scale;

    bf16x8 qhi[2][4], qlo[2][4];
    #pragma unroll
    for (int s = 0; s < 2; ++s) {
        #pragma unroll
        for (int ks = 0; ks < 4; ++ks) {
            const float* qp = Q + inbase + (size_t)(q0w + 16 * s + n) * CEMB + 32 * ks + 8 * quad;
            float4 f0 = *(const float4*)qp;
            float4 f1 = *(const float4*)(qp + 4);
            float fv[8] = {f0.x, f0.y, f0.z, f0.w, f1.x, f1.y, f1.z, f1.w};
            bf16x8 h8, l8;
            #pragma unroll
            for (int j = 0; j < 8; ++j) {
                short hj, lj;
                split2(fv[j], hj, lj);
                h8[j] = hj; l8[j] = lj;
            }
            qhi[s][ks] = h8;
            qlo[s][ks] = l8;
        }
    }

    f32x4 oacc[2][8];
    #pragma unroll
    for (int s = 0; s < 2; ++s)
        #pragma unroll
        for (int nt = 0; nt < 8; ++nt)
            oacc[s][nt] = (f32x4){0.f, 0.f, 0.f, 0.f};

    float m_r[2][4], l_r[2][4];
    #pragma unroll
    for (int s = 0; s < 2; ++s)
        #pragma unroll
        for (int reg = 0; reg < 4; ++reg) { m_r[s][reg] = NEGF; l_r[s][reg] = 0.f; }

    const int nkt = 4 * (qblk + 1);

    for (int kt = 0; kt < nkt; ++kt) {
        const int k0 = kt * 32;
        __syncthreads();
        #pragma unroll
        for (int it = 0; it < 4; ++it) {
            int idx = tid + 256 * it;
            int r   = idx >> 5;
            int c4  = idx & 31;
            size_t off = inbase + (size_t)(k0 + r) * CEMB + 4 * c4;
            float4 kv = *(const float4*)(K + off);
            float4 vv = *(const float4*)(V + off);
            short4 khi4, klo4;
            split2(kv.x, khi4.x, klo4.x); split2(kv.y, khi4.y, klo4.y);
            split2(kv.z, khi4.z, klo4.z); split2(kv.w, khi4.w, klo4.w);
            *(short4*)&Khi[r][4 * c4] = khi4;
            *(short4*)&Klo[r][4 * c4] = klo4;
            int pos = 8 * (it ^ (c4 & 3)) + (r & 7);
            Vt[4 * c4 + 0][pos] = f2bf(vv.x);
            Vt[4 * c4 + 1][pos] = f2bf(vv.y);
            Vt[4 * c4 + 2][pos] = f2bf(vv.z);
            Vt[4 * c4 + 3][pos] = f2bf(vv.w);
        }
        __syncthreads();

        if (k0 <= q0w + 31) {
            f32x4 sacc[2][2];
            #pragma unroll
            for (int s = 0; s < 2; ++s)
                #pragma unroll
                for (int nt = 0; nt < 2; ++nt)
                    sacc[s][nt] = (f32x4){0.f, 0.f, 0.f, 0.f};

            __builtin_amdgcn_s_setprio(1);
            #pragma unroll
            for (int ks = 0; ks < 4; ++ks) {
                #pragma unroll
                for (int nt = 0; nt < 2; ++nt) {
                    bf16x8 khf = *(const bf16x8*)&Khi[16 * nt + n][32 * ks + 8 * quad];
                    bf16x8 klf = *(const bf16x8*)&Klo[16 * nt + n][32 * ks + 8 * quad];
                    #pragma unroll
                    for (int s = 0; s < 2; ++s) {
                        sacc[s][nt] = __builtin_amdgcn_mfma_f32_16x16x32_bf16(qhi[s][ks], khf, sacc[s][nt], 0, 0, 0);
                        sacc[s][nt] = __builtin_amdgcn_mfma_f32_16x16x32_bf16(qhi[s][ks], klf, sacc[s][nt], 0, 0, 0);
                        sacc[s][nt] = __builtin_amdgcn_mfma_f32_16x16x32_bf16(qlo[s][ks], khf, sacc[s][nt], 0, 0, 0);
                        sacc[s][nt] = __builtin_amdgcn_mfma_f32_16x16x32_bf16(qlo[s][ks], klf, sacc[s][nt], 0, 0, 0);
                    }
                }
            }
            __builtin_amdgcn_s_setprio(0);

            #pragma unroll
            for (int s = 0; s < 2; ++s) {
                float sc[2][4];
                #pragma unroll
                for (int nt = 0; nt < 2; ++nt) {
                    #pragma unroll
                    for (int reg = 0; reg < 4; ++reg) {
                        int qrow = q0w + 16 * s + 4 * quad + reg;
                        int kcol = k0 + 16 * nt + n;
                        if (kcol > qrow) { sc[nt][reg] = NEGF; continue; }
                        float sv = sacc[s][nt][reg] * inv_scale;
                        float f  = floorf(sv);
                        float fr = sv - f;
                        if (fr < WIN || fr > 1.0f - WIN) {
                            const float4* qp4 = (const float4*)(Q + inbase + (size_t)qrow * CEMB);
                            const float4* kp4 = (const float4*)(K + inbase + (size_t)kcol * CEMB);
                            double d0 = 0.0, d1 = 0.0, d2 = 0.0, d3 = 0.0;
                            #pragma unroll 2
                            for (int kk = 0; kk < HD / 4; ++kk) {
                                float4 aq = qp4[kk];
                                float4 bk = kp4[kk];
                                d0 += (double)aq.x * bk.x;
                                d1 += (double)aq.y * bk.y;
                                d2 += (double)aq.z * bk.z;
                                d3 += (double)aq.w * bk.w;
                            }
                            f = (float)floor(((d0 + d1) + (d2 + d3)) / dscale);
                        }
                        sc[nt][reg] = f;
                    }
                }
                float alphaL[4];
                #pragma unroll
                for (int reg = 0; reg < 4; ++reg) {
                    float tm = fmaxf(sc[0][reg], sc[1][reg]);
                    tm = fmaxf(tm, __shfl_xor(tm, 1));
                    tm = fmaxf(tm, __shfl_xor(tm, 2));
                    tm = fmaxf(tm, __shfl_xor(tm, 4));
                    tm = fmaxf(tm, __shfl_xor(tm, 8));
                    float mo = m_r[s][reg];
                    float mn = fmaxf(mo, tm);
                    float al = __expf(mo - mn);
                    float p0 = __expf(sc[0][reg] - mn);
                    float p1 = __expf(sc[1][reg] - mn);
                    float ps = p0 + p1;
                    ps += __shfl_xor(ps, 1);
                    ps += __shfl_xor(ps, 2);
                    ps += __shfl_xor(ps, 4);
                    ps += __shfl_xor(ps, 8);
                    l_r[s][reg] = l_r[s][reg] * al + ps;
                    m_r[s][reg] = mn;
                    alphaL[reg] = al;
                    Ps[wave][16 * s + 4 * quad + reg][n]      = f2bf(p0);
                    Ps[wave][16 * s + 4 * quad + reg][16 + n] = f2bf(p1);
                }
                if (!__all(alphaL[0] == 1.0f && alphaL[1] == 1.0f &&
                           alphaL[2] == 1.0f && alphaL[3] == 1.0f)) {
                    #pragma unroll
                    for (int ntv = 0; ntv < 8; ++ntv) {
                        #pragma unroll
                        for (int reg = 0; reg < 4; ++reg)
                            oacc[s][ntv][reg] *= alphaL[reg];
                    }
                }
            }

            bf16x8 pfa[2];
            pfa[0] = *(const bf16x8*)&Ps[wave][n][8 * quad];
            pfa[1] = *(const bf16x8*)&Ps[wave][16 + n][8 * quad];
            __builtin_amdgcn_s_setprio(1);
            #pragma unroll
            for (int ntv = 0; ntv < 8; ++ntv) {
                bf16x8 vf = *(const bf16x8*)&Vt[16 * ntv + n][8 * (quad ^ (n >> 2))];
                oacc[0][ntv] = __builtin_amdgcn_mfma_f32_16x16x32_bf16(pfa[0], vf, oacc[0][ntv], 0, 0, 0);
                oacc[1][ntv] = __builtin_amdgcn_mfma_f32_16x16x32_bf16(pfa[1], vf, oacc[1][ntv], 0, 0, 0);
            }
            __builtin_amdgcn_s_setprio(0);
        }
    }

    #pragma unroll
    for (int s = 0; s < 2; ++s) {
        #pragma unroll
        for (int reg = 0; reg < 4; ++reg) {
            float inv = 1.0f / l_r[s][reg];
            int qrow = q0w + 16 * s + 4 * quad + reg;
            __hip_bfloat16* op = O + ((size_t)b * TSEQ + qrow) * CEMB + (size_t)h * HD;
            #pragma unroll
            for (int ntv = 0; ntv < 8; ++ntv)
                op[16 * ntv + n] = __float2bfloat16(oacc[s][ntv][reg] * inv);
        }
    }
}

// ---------------- W fp32 -> bf16 one-shot conversion ----------------
__global__ __launch_bounds__(256)
void wconv(const float* __restrict__ W, __hip_bfloat16* __restrict__ Wb)
{
    size_t i = ((size_t)blockIdx.x * 256 + threadIdx.x) * 4;
    float4 w = *(const float4*)(W + i);
    short4 s4;
    s4.x = f2bf(w.x); s4.y = f2bf(w.y); s4.z = f2bf(w.z); s4.w = f2bf(w.w);
    *(short4*)(Wb + i) = s4;
}

// ---------------- projection: out = X(bf16) @ Wb(bf16)^T + bias ----------------
__global__ __launch_bounds__(256)
void proj_bf16w(const __hip_bfloat16* __restrict__ X, const __hip_bfloat16* __restrict__ Wb,
                const float* __restrict__ bias, float* __restrict__ out)
{
    __shared__ __align__(16) short Xs[128][40];
    __shared__ __align__(16) short Ws[128][40];

    const int tid  = threadIdx.x;
    const int wave = tid >> 6;
    const int lane = tid & 63;
    const int quad = lane >> 4;
    const int n    = lane & 15;
    const int wm   = wave >> 1;
    const int wn   = wave & 1;

    const int m0 = blockIdx.y * 128;
    const int n0 = blockIdx.x * 128;

    f32x4 acc[4][4];
    #pragma unroll
    for (int i = 0; i < 4; ++i)
        #pragma unroll
        for (int j = 0; j < 4; ++j)
            acc[i][j] = (f32x4){0.f, 0.f, 0.f, 0.f};

    for (int k0 = 0; k0 < CEMB; k0 += 32) {
        __syncthreads();
        #pragma unroll
        for (int ii = 0; ii < 2; ++ii) {
            int idx = tid + 256 * ii;          // 0..511
            int row = idx >> 2;                // 0..127
            int c   = idx & 3;                 // 16B group
            *(bf16x8*)&Xs[row][8 * c] =
                *(const bf16x8*)(X + (size_t)(m0 + row) * CEMB + k0 + 8 * c);
            *(bf16x8*)&Ws[row][8 * c] =
                *(const bf16x8*)(Wb + (size_t)(n0 + row) * CEMB + k0 + 8 * c);
        }
        __syncthreads();

        bf16x8 a[4], bb[4];
        #pragma unroll
        for (int i = 0; i < 4; ++i)
            a[i] = *(const bf16x8*)&Xs[64 * wm + 16 * i + n][8 * quad];
        #pragma unroll
        for (int j = 0; j < 4; ++j)
            bb[j] = *(const bf16x8*)&Ws[64 * wn + 16 * j + n][8 * quad];
        __builtin_amdgcn_s_setprio(1);
        #pragma unroll
        for (int i = 0; i < 4; ++i)
            #pragma unroll
            for (int j = 0; j < 4; ++j)
                acc[i][j] = __builtin_amdgcn_mfma_f32_16x16x32_bf16(a[i], bb[j], acc[i][j], 0, 0, 0);
        __builtin_amdgcn_s_setprio(0);
    }

    #pragma unroll
    for (int j = 0; j < 4; ++j) {
        int col = n0 + 64 * wn + 16 * j + n;
        float bj = bias[col];
        #pragma unroll
        for (int i = 0; i < 4; ++i) {
            #pragma unroll
            for (int reg = 0; reg < 4; ++reg) {
                int row = m0 + 64 * wm + 16 * i + 4 * quad + reg;
                out[(size_t)row * CEMB + col] = acc[i][j][reg] + bj;
            }
        }
    }
}

// ---------------- fallback projection with fp32 W (small ws_size) ----------------
__global__ __launch_bounds__(256)
void proj_mfma(const __hip_bfloat16* __restrict__ X, const float* __restrict__ W,
               const float* __restrict__ bias, float* __restrict__ out)
{
    __shared__ __align__(16) short Xs[128][40];
    __shared__ __align__(16) short Ws[128][40];

    const int tid  = threadIdx.x;
    const int wave = tid >> 6;
    const int lane = tid & 63;
    const int quad = lane >> 4;
    const int n    = lane & 15;
    const int wm   = wave >> 1;
    const int wn   = wave & 1;

    const int m0 = blockIdx.y * 128;
    const int n0 = blockIdx.x * 128;

    f32x4 acc[4][4];
    #pragma unroll
    for (int i = 0; i < 4; ++i)
        #pragma unroll
        for (int j = 0; j < 4; ++j)
            acc[i][j] = (f32x4){0.f, 0.f, 0.f, 0.f};

    for (int k0 = 0; k0 < CEMB; k0 += 32) {
        __syncthreads();
        #pragma unroll
        for (int ii = 0; ii < 2; ++ii) {
            int idx = tid + 256 * ii;
            int row = idx >> 2;
            int c   = idx & 3;
            *(bf16x8*)&Xs[row][8 * c] =
                *(const bf16x8*)(X + (size_t)(m0 + row) * CEMB + k0 + 8 * c);
        }
        #pragma unroll
        for (int ii = 0; ii < 4; ++ii) {
            int idx = tid + 256 * ii;
            int row = idx >> 3;
            int c4  = idx & 7;
            float4 wv = *(const float4*)(W + (size_t)(n0 + row) * CEMB + k0 + 4 * c4);
            short4 w4;
            w4.x = f2bf(wv.x); w4.y = f2bf(wv.y); w4.z = f2bf(wv.z); w4.w = f2bf(wv.w);
            *(short4*)&Ws[row][4 * c4] = w4;
        }
        __syncthreads();

        bf16x8 a[4], bb[4];
        #pragma unroll
        for (int i = 0; i < 4; ++i)
            a[i] = *(const bf16x8*)&Xs[64 * wm + 16 * i + n][8 * quad];
        #pragma unroll
        for (int j = 0; j < 4; ++j)
            bb[j] = *(const bf16x8*)&Ws[64 * wn + 16 * j + n][8 * quad];
        #pragma unroll
        for (int i = 0; i < 4; ++i)
            #pragma unroll
            for (int j = 0; j < 4; ++j)
                acc[i][j] = __builtin_amdgcn_mfma_f32_16x16x32_bf16(a[i], bb[j], acc[i][j], 0, 0, 0);
    }

    #pragma unroll
    for (int j = 0; j < 4; ++j) {
        int col = n0 + 64 * wn + 16 * j + n;
        float bj = bias[col];
        #pragma unroll
        for (int i = 0; i < 4; ++i) {
            #pragma unroll
            for (int reg = 0; reg < 4; ++reg) {
                int row = m0 + 64 * wm + 16 * i + 4 * quad + reg;
                out[(size_t)row * CEMB + col] = acc[i][j][reg] + bj;
            }
        }
    }
}

extern "C" void kernel_launch(void* const* d_in, const int* in_sizes, int n_in,
                              void* d_out, int out_size, void* d_ws, size_t ws_size,
                              hipStream_t stream)
{
    // setup_inputs order: v, k, q, W_out, b_out
    const float* v    = (const float*)d_in[0];
    const float* k    = (const float*)d_in[1];
    const float* q    = (const float*)d_in[2];
    const float* W    = (const float*)d_in[3];
    const float* bias = (const float*)d_in[4];

    const size_t attn_bytes = (size_t)BATCH * TSEQ * CEMB * 2;       // 32 MiB
    const size_t wb_bytes   = (size_t)CEMB * CEMB * 2;               //  8 MiB
    const size_t kh_bytes   = (size_t)64 * TSEQ * 128 * 2;           // 32 MiB
    const size_t vt_bytes   = (size_t)64 * 64 * 4096 * 2;            // 32 MiB

    __hip_bfloat16* attn = (__hip_bfloat16*)d_ws;
    float* out = (float*)d_out;

    dim3 pgrid(CEMB / 128, (BATCH * TSEQ) / 128);   // (16, 64)

    if (ws_size >= attn_bytes + wb_bytes + 2 * kh_bytes + vt_bytes) {
        char* p = (char*)d_ws;
        __hip_bfloat16* Wb   = (__hip_bfloat16*)(p + attn_bytes);
        __hip_bfloat16* Khig = (__hip_bfloat16*)(p + attn_bytes + wb_bytes);
        __hip_bfloat16* Klog = (__hip_bfloat16*)(p + attn_bytes + wb_bytes + kh_bytes);
        __hip_bfloat16* Vtg  = (__hip_bfloat16*)(p + attn_bytes + wb_bytes + 2 * kh_bytes);
        kvconv<<<dim3(4096), 256, 0, stream>>>(k, v, Khig, Klog, Vtg);
        wconv<<<dim3(CEMB * CEMB / 1024), 256, 0, stream>>>(W, Wb);
        attn_mfma<<<dim3(1024), 256, 0, stream>>>(q, k, Khig, Klog, Vtg, attn);
        proj_bf16w<<<pgrid, 256, 0, stream>>>(attn, Wb, bias, out);
    } else if (ws_size >= attn_bytes + wb_bytes) {
        __hip_bfloat16* Wb = (__hip_bfloat16*)((char*)d_ws + attn_bytes);
        wconv<<<dim3(CEMB * CEMB / 1024), 256, 0, stream>>>(W, Wb);
        attn_mfma_fb<<<dim3(1024), 256, 0, stream>>>(q, k, v, attn);
        proj_bf16w<<<pgrid, 256, 0, stream>>>(attn, Wb, bias, out);
    } else {
        attn_mfma_fb<<<dim3(1024), 256, 0, stream>>>(q, k, v, attn);
        proj_mfma<<<pgrid, 256, 0, stream>>>(attn, W, bias, out);
    }
}